// Round 3
// baseline (1151.460 us; speedup 1.0000x reference)
//
#include <hip/hip_runtime.h>
#include <math.h>

#define B_ 8
#define N_ 16384
#define D_ 384
#define TD_ 1152
#define M_ (B_*N_)
#define CTX_ELEMS (B_*8*48*48)    /* 147456 fp32 */
#define Z_ELEMS   (B_*8*48)       /* 3072 fp32   */

typedef __attribute__((ext_vector_type(8))) short short8;
typedef __attribute__((ext_vector_type(4))) float f32x4;
typedef __attribute__((ext_vector_type(4))) unsigned short us4;
typedef __attribute__((ext_vector_type(8))) unsigned short us8;

__device__ __forceinline__ unsigned short f2bf(float f){
    union { float f; unsigned u; } v; v.f = f;
    unsigned r = v.u + 0x7FFFu + ((v.u >> 16) & 1u);   // RNE
    return (unsigned short)(r >> 16);
}

#define MFMA(a,b,c) __builtin_amdgcn_mfma_f32_16x16x32_bf16((a),(b),(c),0,0,0)

// ---------------------------------------------------------------------------
// kP: transpose + bf16-ify weights. WqkvT[col][d] (1152x384), WpT[col][d] (384x384)
// ---------------------------------------------------------------------------
__global__ void kP(const float* __restrict__ Wqkv, const float* __restrict__ Wp,
                   unsigned short* __restrict__ WqkvT, unsigned short* __restrict__ WpT)
{
    __shared__ float t[32][33];
    int bi = blockIdx.x;
    const float* src; unsigned short* dst; int ldS, c0, d0;
    if (bi < 432) { src = Wqkv; dst = WqkvT; ldS = 1152; c0 = (bi % 36) * 32; d0 = (bi / 36) * 32; }
    else { bi -= 432; src = Wp; dst = WpT; ldS = 384; c0 = (bi % 12) * 32; d0 = (bi / 12) * 32; }
    const int cx = threadIdx.x & 31, ry = threadIdx.x >> 5;
#pragma unroll
    for (int k = 0; k < 4; ++k) {
        int r = ry + k * 8;
        t[r][cx] = src[(size_t)(d0 + r) * ldS + c0 + cx];
    }
    __syncthreads();
#pragma unroll
    for (int k = 0; k < 4; ++k) {
        int r = ry + k * 8;
        dst[(size_t)(c0 + r) * 384 + d0 + cx] = f2bf(t[cx][r]);
    }
}

// ---------------------------------------------------------------------------
// kA: 512 blocks x 512 thr (8 waves, wave = head), 8 token-tiles of 32 each.
// Per tile: stage x (2 barriers) -> k,v GEMM (split halves) -> exp/pack into
// per-wave swizzled LDS (NO barriers, wave-local) -> ctx MFMA accumulate.
// LDS 74.2 KB -> 2 blocks/CU (16 waves).
// ---------------------------------------------------------------------------
__global__ __launch_bounds__(512, 4) void kA(const float* __restrict__ x,
        const unsigned short* __restrict__ WqkvT,
        float* __restrict__ ctx, float* __restrict__ Z)
{
    __shared__ __align__(16) unsigned short xs[32 * 392];      // 25088 B, [t][d]
    __shared__ __align__(16) unsigned short kv[8 * 96 * 32];   // 49152 B, per-wave [row][t32] swizzled

    const int tid = threadIdx.x;
    const int w   = tid >> 6;       // wave = head
    const int l   = tid & 63;
    const int q   = l >> 4;
    const int c16 = l & 15;
    const int blk = blockIdx.x;
    const int b   = blk >> 6;             // 64 blocks per batch
    const int tile0 = (blk & 63) * 8;
    unsigned short* kvw = kv + w * (96 * 32);

    f32x4 ctxacc[3][3];
    float zp[3] = {0.f, 0.f, 0.f};
#pragma unroll
    for (int i = 0; i < 3; ++i)
#pragma unroll
        for (int j = 0; j < 3; ++j) ctxacc[i][j] = (f32x4){0.f, 0.f, 0.f, 0.f};

    const int st = tid >> 4, sq = tid & 15;   // staging: 32 rows x 16 lanes

    for (int g = 0; g < 8; ++g) {
        const size_t tok0 = (size_t)b * 16384 + (size_t)(tile0 + g) * 32;
        __syncthreads();
        {   // stage x tile -> bf16 LDS
            const float* xg = x + (tok0 + st) * 384 + sq * 4;
            unsigned short* xw = xs + st * 392 + sq * 4;
#pragma unroll
            for (int i = 0; i < 6; ++i) {
                float4 v = *(const float4*)(xg + i * 64);
                us4 o; o.x = f2bf(v.x); o.y = f2bf(v.y); o.z = f2bf(v.z); o.w = f2bf(v.w);
                *(us4*)(xw + i * 64) = o;
            }
        }
        __syncthreads();

        // --- k,v GEMM in two halves (half 0 = k cols, half 1 = v cols) ---
#pragma unroll
        for (int half = 0; half < 2; ++half) {
            f32x4 acc2[2][3];
#pragma unroll
            for (int mt = 0; mt < 2; ++mt)
#pragma unroll
                for (int j = 0; j < 3; ++j) acc2[mt][j] = (f32x4){0.f, 0.f, 0.f, 0.f};

#pragma unroll
            for (int ks = 0; ks < 12; ++ks) {
                short8 a0 = *(const short8*)(xs + (c16) * 392 + ks * 32 + q * 8);
                short8 a1 = *(const short8*)(xs + (16 + c16) * 392 + ks * 32 + q * 8);
#pragma unroll
                for (int j = 0; j < 3; ++j) {
                    const int col = 384 + half * 384 + w * 48 + j * 16 + c16;
                    short8 bf = *(const short8*)(WqkvT + (size_t)col * 384 + ks * 32 + q * 8);
                    acc2[0][j] = MFMA(a0, bf, acc2[0][j]);
                    acc2[1][j] = MFMA(a1, bf, acc2[1][j]);
                }
            }

            // pack (exp for k-half) into per-wave swizzled kv — wave-local, no barrier
#pragma unroll
            for (int mt = 0; mt < 2; ++mt) {
                const int t8  = mt * 2 + (q >> 1);
                const int tin = (q & 1) * 4;
#pragma unroll
                for (int j = 0; j < 3; ++j) {
                    f32x4 vv = acc2[mt][j];
                    const int row = half * 48 + j * 16 + c16;
                    us4 o;
                    if (half == 0) {
                        float e0 = __expf(vv.x), e1 = __expf(vv.y), e2 = __expf(vv.z), e3 = __expf(vv.w);
                        zp[j] += (e0 + e1) + (e2 + e3);
                        o.x = f2bf(e0); o.y = f2bf(e1); o.z = f2bf(e2); o.w = f2bf(e3);
                    } else {
                        o.x = f2bf(vv.x); o.y = f2bf(vv.y); o.z = f2bf(vv.z); o.w = f2bf(vv.w);
                    }
                    *(us4*)(kvw + row * 32 + (((t8 ^ (row & 3))) << 3) + tin) = o;
                }
            }
        }

        // --- ctx MFMA: one K=32 step per (ct,dt); wave-local lgkmcnt ordering ---
        short8 af[3], bf2[3];
#pragma unroll
        for (int i = 0; i < 3; ++i) {
            const int ra = i * 16 + c16;
            af[i]  = *(const short8*)(kvw + ra * 32 + ((q ^ (ra & 3)) << 3));
            const int rb = 48 + i * 16 + c16;
            bf2[i] = *(const short8*)(kvw + rb * 32 + ((q ^ (rb & 3)) << 3));
        }
#pragma unroll
        for (int ct = 0; ct < 3; ++ct)
#pragma unroll
            for (int dt = 0; dt < 3; ++dt)
                ctxacc[ct][dt] = MFMA(af[ct], bf2[dt], ctxacc[ct][dt]);
    }

    // --- finalize: Z and ctx atomics ---
#pragma unroll
    for (int j = 0; j < 3; ++j) {
        float v = zp[j];
        v += __shfl_xor(v, 16);
        v += __shfl_xor(v, 32);
        if (l < 16) atomicAdd(&Z[(b * 8 + w) * 48 + j * 16 + c16], v);
    }
#pragma unroll
    for (int ct = 0; ct < 3; ++ct)
#pragma unroll
        for (int dt = 0; dt < 3; ++dt)
#pragma unroll
            for (int r = 0; r < 4; ++r) {
                const int c = ct * 16 + q * 4 + r;
                const int d = dt * 16 + c16;
                atomicAdd(&ctx[((size_t)(b * 8 + w) * 48 + c) * 48 + d], ctxacc[ct][dt][r]);
            }
}

// ---------------------------------------------------------------------------
// kB: ctxT[bh][d][c(pad 64)] = bf16( ctx[bh][c][d] / Z[bh][c] ), pad zeros.
// ---------------------------------------------------------------------------
__global__ void kB(const float* __restrict__ ctx, const float* __restrict__ Z,
                   unsigned short* __restrict__ ctxT)
{
    const int e = blockIdx.x * 256 + threadIdx.x;    // < 196608
    const int bh = e / 3072;
    const int r = e % 3072;
    const int d = r >> 6;
    const int c = r & 63;
    float v = 0.f;
    if (c < 48) v = ctx[((size_t)bh * 48 + c) * 48 + d] / Z[bh * 48 + c];
    ctxT[e] = f2bf(v);
}

// ---------------------------------------------------------------------------
// kC: per 32-token block (256 thr = 4 waves, wave = 2 heads), per-head q̂
// roundtrip buffer (wave-private, no barriers) -> 43.5 KB LDS -> 3 blocks/CU.
// Barriers: stage, S1 (xs reuse as y), S2 (y complete). grid = 4096.
// ---------------------------------------------------------------------------
__global__ __launch_bounds__(256, 3) void kC(const float* __restrict__ x,
        const unsigned short* __restrict__ WqkvT,
        const unsigned short* __restrict__ ctxT,
        const unsigned short* __restrict__ WpT,
        const float* __restrict__ bp, float* __restrict__ out)
{
    __shared__ __align__(16) unsigned short xs[32 * 392];    // 25088 B: x tile, then y tile
    __shared__ __align__(16) unsigned short qs[4 * 32 * 72]; // 18432 B: per-wave q̂ [t][c64+pad8]

    const int tid = threadIdx.x;
    const int w   = tid >> 6;
    const int l   = tid & 63;
    const int q   = l >> 4;
    const int c16 = l & 15;
    const int blk = blockIdx.x;
    const size_t tok0 = (size_t)blk * 32;
    const int b = blk >> 9;
    unsigned short* qsw = qs + w * (32 * 72);

    {   // stage x
        const int st = tid >> 3, sq = tid & 7;
        const float* xg = x + (tok0 + st) * 384 + sq * 4;
        unsigned short* xw = xs + st * 392 + sq * 4;
#pragma unroll
        for (int i = 0; i < 12; ++i) {
            float4 v = *(const float4*)(xg + i * 32);
            us4 o; o.x = f2bf(v.x); o.y = f2bf(v.y); o.z = f2bf(v.z); o.w = f2bf(v.w);
            *(us4*)(xw + i * 32) = o;
        }
    }
    __syncthreads();

    // --- q-GEMM: 32 tok x 96 cols per wave (heads 2w, 2w+1), K=384 ---
    f32x4 acc[2][6];
#pragma unroll
    for (int mt = 0; mt < 2; ++mt)
#pragma unroll
        for (int j = 0; j < 6; ++j) acc[mt][j] = (f32x4){0.f, 0.f, 0.f, 0.f};

#pragma unroll
    for (int ks = 0; ks < 12; ++ks) {
        short8 a0 = *(const short8*)(xs + (c16) * 392 + ks * 32 + q * 8);
        short8 a1 = *(const short8*)(xs + (16 + c16) * 392 + ks * 32 + q * 8);
#pragma unroll
        for (int j = 0; j < 6; ++j) {
            const int nt = w * 6 + j;
            short8 bf = *(const short8*)(WqkvT + (size_t)(nt * 16 + c16) * 384 + ks * 32 + q * 8);
            acc[0][j] = MFMA(a0, bf, acc[0][j]);
            acc[1][j] = MFMA(a1, bf, acc[1][j]);
        }
    }
    __syncthreads();    // S1: all waves done reading xs; xs becomes y buffer

    {   // zero qs K-pad (c in [48,64)) once — wave-local
        const int t = l & 31, p = l >> 5;
        us8 z8 = {0, 0, 0, 0, 0, 0, 0, 0};
        *(us8*)(qsw + t * 72 + 48 + p * 8) = z8;
    }

    // --- per head: softmax -> q̂ roundtrip (wave-local) -> y = q̂@ctx̂ -> y into xs ---
#pragma unroll
    for (int hh = 0; hh < 2; ++hh) {
        const int h = 2 * w + hh;
        f32x4 e[2][3];
#pragma unroll
        for (int mt = 0; mt < 2; ++mt)
#pragma unroll
            for (int jj = 0; jj < 3; ++jj) {
                f32x4 vv = acc[mt][hh * 3 + jj];
                e[mt][jj].x = __expf(vv.x); e[mt][jj].y = __expf(vv.y);
                e[mt][jj].z = __expf(vv.z); e[mt][jj].w = __expf(vv.w);
            }
#pragma unroll
        for (int mt = 0; mt < 2; ++mt)
#pragma unroll
            for (int r = 0; r < 4; ++r) {
                float s = e[mt][0][r] + e[mt][1][r] + e[mt][2][r];
                s += __shfl_xor(s, 1); s += __shfl_xor(s, 2);
                s += __shfl_xor(s, 4); s += __shfl_xor(s, 8);
                const float inv = 1.0f / s;
                e[mt][0][r] *= inv; e[mt][1][r] *= inv; e[mt][2][r] *= inv;
            }
        // write q̂ into per-wave buffer [t][c]
#pragma unroll
        for (int mt = 0; mt < 2; ++mt)
#pragma unroll
            for (int jj = 0; jj < 3; ++jj) {
                const int c = jj * 16 + c16;
#pragma unroll
                for (int r = 0; r < 4; ++r) {
                    const int t = mt * 16 + q * 4 + r;
                    qsw[t * 72 + c] = f2bf(e[mt][jj][r]);
                }
            }

        // y-GEMM (K=64 padded); compiler inserts lgkmcnt for the wave-local roundtrip
        f32x4 y[2][3];
#pragma unroll
        for (int mt = 0; mt < 2; ++mt)
#pragma unroll
            for (int dt = 0; dt < 3; ++dt) y[mt][dt] = (f32x4){0.f, 0.f, 0.f, 0.f};
#pragma unroll
        for (int ks = 0; ks < 2; ++ks) {
            short8 a0 = *(const short8*)(qsw + (c16) * 72 + ks * 32 + q * 8);
            short8 a1 = *(const short8*)(qsw + (16 + c16) * 72 + ks * 32 + q * 8);
#pragma unroll
            for (int dt = 0; dt < 3; ++dt) {
                short8 bf = *(const short8*)(ctxT + ((size_t)(b * 8 + h) * 48 + dt * 16 + c16) * 64 + ks * 32 + q * 8);
                y[0][dt] = MFMA(a0, bf, y[0][dt]);
                y[1][dt] = MFMA(a1, bf, y[1][dt]);
            }
        }
#pragma unroll
        for (int mt = 0; mt < 2; ++mt)
#pragma unroll
            for (int dt = 0; dt < 3; ++dt) {
                const int dcol = h * 48 + dt * 16 + c16;
#pragma unroll
                for (int r = 0; r < 4; ++r) {
                    const int t = mt * 16 + q * 4 + r;
                    xs[t * 392 + dcol] = f2bf(y[mt][dt][r]);
                }
            }
    }
    __syncthreads();    // S2: y complete across waves

    // --- proj: out = y @ Wp + b, 32 tok x 96 cols per wave, K=384 ---
    f32x4 po[2][6];
#pragma unroll
    for (int mt = 0; mt < 2; ++mt)
#pragma unroll
        for (int j = 0; j < 6; ++j) po[mt][j] = (f32x4){0.f, 0.f, 0.f, 0.f};

#pragma unroll
    for (int ks = 0; ks < 12; ++ks) {
        short8 a0 = *(const short8*)(xs + (c16) * 392 + ks * 32 + q * 8);
        short8 a1 = *(const short8*)(xs + (16 + c16) * 392 + ks * 32 + q * 8);
#pragma unroll
        for (int j = 0; j < 6; ++j) {
            const int nt = w * 6 + j;
            short8 bf = *(const short8*)(WpT + (size_t)(nt * 16 + c16) * 384 + ks * 32 + q * 8);
            po[0][j] = MFMA(a0, bf, po[0][j]);
            po[1][j] = MFMA(a1, bf, po[1][j]);
        }
    }

    // --- epilogue: bias + store ---
#pragma unroll
    for (int j = 0; j < 6; ++j) {
        const int col = (w * 6 + j) * 16 + c16;
        const float bv = bp[col];
#pragma unroll
        for (int mt = 0; mt < 2; ++mt)
#pragma unroll
            for (int r = 0; r < 4; ++r) {
                const int t = mt * 16 + q * 4 + r;
                out[(tok0 + t) * 384 + col] = po[mt][j][r] + bv;
            }
    }
}

// ---------------------------------------------------------------------------
extern "C" void kernel_launch(void* const* d_in, const int* in_sizes, int n_in,
                              void* d_out, int out_size, void* d_ws, size_t ws_size,
                              hipStream_t stream)
{
    (void)in_sizes; (void)n_in; (void)out_size; (void)ws_size;
    const float* x    = (const float*)d_in[0];
    const float* Wqkv = (const float*)d_in[1];
    const float* Wp   = (const float*)d_in[2];
    const float* bp   = (const float*)d_in[3];
    float* out = (float*)d_out;

    char* p = (char*)d_ws;
    float* ctx = (float*)p;                 p += CTX_ELEMS * 4;     // 589824 B
    float* Z   = (float*)p;                 p += Z_ELEMS * 4;       // 12288 B
    unsigned short* WqkvT = (unsigned short*)p;  p += TD_ * D_ * 2;      // 884736 B
    unsigned short* WpT   = (unsigned short*)p;  p += D_ * D_ * 2;       // 294912 B
    unsigned short* ctxT  = (unsigned short*)p;                          // 393216 B

    hipMemsetAsync(d_ws, 0, (CTX_ELEMS + Z_ELEMS) * sizeof(float), stream);
    kP<<<dim3(576), dim3(256), 0, stream>>>(Wqkv, Wp, WqkvT, WpT);
    kA<<<dim3(512), dim3(512), 0, stream>>>(x, WqkvT, ctx, Z);
    kB<<<dim3(768), dim3(256), 0, stream>>>(ctx, Z, ctxT);
    kC<<<dim3(4096), dim3(256), 0, stream>>>(x, WqkvT, ctxT, WpT, bp, out);
}